// Round 9
// baseline (365.404 us; speedup 1.0000x reference)
//
#include <hip/hip_runtime.h>
#include <hip/hip_bf16.h>
#include <stdint.h>

typedef short bf16x8 __attribute__((ext_vector_type(8)));   // 8 bf16 in 4 VGPRs
typedef float f32x4 __attribute__((ext_vector_type(4)));
typedef float f32v4 __attribute__((ext_vector_type(4)));
typedef unsigned short u16;
typedef u16 ushort8 __attribute__((ext_vector_type(8)));

typedef __attribute__((address_space(3))) void lds_void;
typedef const __attribute__((address_space(1))) void gbl_void;

#define BAR() do { asm volatile("" ::: "memory"); __builtin_amdgcn_s_barrier(); asm volatile("" ::: "memory"); } while (0)
#define WAITV(N) asm volatile("s_waitcnt vmcnt(" #N ")" ::: "memory")
#define LGKM0() asm volatile("s_waitcnt lgkmcnt(0)" ::: "memory")

__device__ __forceinline__ u16 f2bf(float f) {
  uint32_t u = __builtin_bit_cast(uint32_t, f);
  u += 0x7fffu + ((u >> 16) & 1u);   // round-to-nearest-even
  return (u16)(u >> 16);
}

// ---------------- build Mt[j][i] = M[i][j] (bf16, 4096x4096) ----------------
__global__ __launch_bounds__(256) void build_mt(
    const float* __restrict__ c0, const float* __restrict__ c1,
    const float* __restrict__ c2, const float* __restrict__ c3,
    u16* __restrict__ Mt) {
  const int bid = blockIdx.x;
  const int j1 = bid & 7, i1 = (bid >> 3) & 7, j0 = (bid >> 6) & 7, i0 = bid >> 9;
  const int t = threadIdx.x;
  __shared__ float v[512];   // [i2][j2][r3]
  __shared__ float g3[512];  // copy of c3 [r3][i3][j3]
  g3[t] = c3[t];
  g3[t + 256] = c3[t + 256];
  float w2[8];
#pragma unroll
  for (int r2 = 0; r2 < 8; ++r2) {
    float s = 0.f;
#pragma unroll
    for (int r1 = 0; r1 < 8; ++r1)
      s += c0[(i0 * 8 + j0) * 8 + r1] * c1[((r1 * 8 + i1) * 8 + j1) * 8 + r2];
    w2[r2] = s;
  }
#pragma unroll
  for (int e = t; e < 512; e += 256) {
    const int r3 = e & 7, j2 = (e >> 3) & 7, i2 = e >> 6;
    float s = 0.f;
#pragma unroll
    for (int r2 = 0; r2 < 8; ++r2)
      s += w2[r2] * c2[((r2 * 8 + i2) * 8 + j2) * 8 + r3];
    v[e] = s;
  }
  __syncthreads();
  const int jr = t >> 2, ic0 = (t & 3) * 16;
  const int j2 = jr >> 3, j3 = jr & 7;
  const size_t base =
      (size_t)(j0 * 512 + j1 * 64 + jr) * 4096 + (i0 * 512 + i1 * 64) + ic0;
  ushort8 o0, o1;
#pragma unroll
  for (int q = 0; q < 16; ++q) {
    const int ic = ic0 + q, i2 = ic >> 3, i3 = ic & 7;
    float s = 0.f;
#pragma unroll
    for (int r3 = 0; r3 < 8; ++r3)
      s += v[(i2 << 6) + (j2 << 3) + r3] * g3[(r3 << 6) + (i3 << 3) + j3];
    const u16 h = f2bf(s);
    if (q < 8) o0[q] = h; else o1[q - 8] = h;
  }
  *(ushort8*)(Mt + base) = o0;
  *(ushort8*)(Mt + base + 8) = o1;
}

// ---------------- GEMM: 256x256, BK=64, R6 8-phase + fused f32->bf16 A ------
// A source = x (f32) directly: reg-staged (issue 4x dwordx4 2 phases early ->
// v_cvt_pk_bf16_f32 -> swizzled ds_write_b128) at EXACTLY R6's stage slots,
// so region-safety ledger is unchanged. B stays global_load_lds (pre-swizzled
// source). No vmcnt waits in loop (stages 6-7 phases ahead, latency-covered;
// R6-proven). Phases with ds_writes add lgkmcnt(0) AFTER the MFMA cluster
// (hidden) so writes are visible before the barrier. Swizzle: logical 16B
// chunk c stored at (c ^ (row&7)) for both A (write-side) and B (source-side).
__global__ __launch_bounds__(512, 1) void gemm_bias_relu(
    const float* __restrict__ X, const u16* __restrict__ Bt,
    const float* __restrict__ bias, float* __restrict__ C) {
  constexpr int K = 4096, N = 4096, NT = 64;
  __shared__ __align__(16) char lds[131072];
  const int t = threadIdx.x;
  const int l = t & 63, w = t >> 6;
  const int wr = w >> 2, wc = w & 3;            // 2 x 4 wave grid
  const int lr = l & 15, lk = l >> 4;
  const int bm = blockIdx.y, bn = blockIdx.x;

  const float* gAf = X + (size_t)bm * 256 * K;  // f32 A panel
  const char* gB = (const char*)Bt + (size_t)bn * 256 * (K * 2);
  const int srow = t >> 3;                      // B staging row 0..63
  const int schunk = (t & 7) ^ (srow & 7);      // pre-swizzled source chunk
  const int sgo = srow * (K * 2) + schunk * 16;
  const int sld = t * 16;
  const int ar = t >> 2;                        // A staging row 0..127
  const int aq = t & 3;                         // A quarter (16 floats)

  const int axor = (lk ^ (lr & 7)) * 16;        // kk0 chunk; kk1 = axor ^ 64
  const int aoff0 = (wr * 128 + lr) * 128 + axor;
  const int aoff1 = aoff0 ^ 64;
  const int boff0 = 65536 + (wc * 64 + lr) * 128 + axor;
  const int boff1 = boff0 ^ 64;

  auto aload = [&](f32v4* L, int h, int kt) {   // issue 4x dwordx4 (f32)
    const float* src = gAf + (size_t)(h * 128 + ar) * K + kt * 64 + aq * 16;
#pragma unroll
    for (int j = 0; j < 4; ++j) L[j] = *(const f32v4*)(src + j * 4);
  };
  auto awrite = [&](const f32v4* L, int p, int h) {  // cvt + swizzled ds_write
    uint32_t d[8];
#pragma unroll
    for (int j = 0; j < 4; ++j) {
      asm("v_cvt_pk_bf16_f32 %0, %1, %2" : "=v"(d[2 * j]) : "v"(L[j][0]), "v"(L[j][1]));
      asm("v_cvt_pk_bf16_f32 %0, %1, %2" : "=v"(d[2 * j + 1]) : "v"(L[j][2]), "v"(L[j][3]));
    }
    char* base = lds + p * 32768 + h * 16384 + ar * 128;
    const int s = ar & 7;
    *(uint4*)(base + (((2 * aq) ^ s) * 16)) = make_uint4(d[0], d[1], d[2], d[3]);
    *(uint4*)(base + (((2 * aq + 1) ^ s) * 16)) = make_uint4(d[4], d[5], d[6], d[7]);
  };
  auto stB = [&](int p, int h, int kt) {
    const char* src = gB + (size_t)(h * 128) * (K * 2) + kt * 128 + sgo;
    char* dst = lds + 65536 + p * 32768 + h * 16384 + sld;
    __builtin_amdgcn_global_load_lds((gbl_void*)src, (lds_void*)dst, 16, 0, 0);
    __builtin_amdgcn_global_load_lds((gbl_void*)(src + (size_t)64 * (K * 2)),
                                     (lds_void*)(dst + 8192), 16, 0, 0);
  };
  auto rdA = [&](int p, int off, int m) -> bf16x8 {
    return *(const bf16x8*)(lds + p * 32768 + off + m * 2048);
  };
  auto rdB = [&](int p, int off, int n) -> bf16x8 {
    return *(const bf16x8*)(lds + p * 32768 + off + n * 2048);
  };

  bf16x8 aH0[8], aH1[8], b01[2][2], b23[2][2];
  f32x4 acc[8][4];
#pragma unroll
  for (int m = 0; m < 8; ++m)
#pragma unroll
    for (int n = 0; n < 4; ++n) acc[m][n] = f32x4{0.f, 0.f, 0.f, 0.f};

  auto rdAH = [&](bf16x8* d, int p, int mh) {   // 4m x 2kk = 8 reads
#pragma unroll
    for (int m2 = 0; m2 < 4; ++m2) {
      d[m2 * 2 + 0] = rdA(p, aoff0, mh * 4 + m2);
      d[m2 * 2 + 1] = rdA(p, aoff1, mh * 4 + m2);
    }
  };
  auto rdBH = [&](bf16x8 (*d)[2], int p, int nh) {  // 2n x 2kk = 4 reads
#pragma unroll
    for (int n2 = 0; n2 < 2; ++n2) {
      d[n2][0] = rdB(p, boff0, nh * 2 + n2);
      d[n2][1] = rdB(p, boff1, nh * 2 + n2);
    }
  };
  auto quad = [&](int mh, int nh, bf16x8* aH, bf16x8 (*bH)[2]) {  // 16 MFMA
    __builtin_amdgcn_s_setprio(1);
#pragma unroll
    for (int kk = 0; kk < 2; ++kk)
#pragma unroll
      for (int m2 = 0; m2 < 4; ++m2)
#pragma unroll
        for (int n2 = 0; n2 < 2; ++n2)
          acc[mh * 4 + m2][nh * 2 + n2] = __builtin_amdgcn_mfma_f32_16x16x32_bf16(
              aH[m2 * 2 + kk], bH[n2][kk], acc[mh * 4 + m2][nh * 2 + n2], 0, 0, 0);
    __builtin_amdgcn_s_setprio(0);
  };

  f32v4 L_p2[4], L_p4[4], L_p5[4], L_p1[4];

  // ---- prologue: A loads first (cvt's auto-vmcnt then leaves B in flight) --
  aload(L_p4, 0, 0); aload(L_p5, 1, 0); aload(L_p1, 0, 1); aload(L_p2, 1, 1);
  stB(0, 0, 0); stB(0, 1, 0); stB(1, 0, 1); stB(1, 1, 1);
  awrite(L_p4, 0, 0); awrite(L_p5, 0, 1); awrite(L_p1, 1, 0); awrite(L_p2, 1, 1);
  LGKM0();
  WAITV(4);        // force B tile0; B tile1's 4 loads stay in flight
  BAR();
  // preload tile0 aH0/b01; re-load L_p2 for iter0-P2's benign same-data write
  rdAH(aH0, 0, 0); rdBH(b01, 0, 0);
  aload(L_p2, 1, 1);
  BAR();

  for (int it = 0; it < NT / 2; ++it) {
    const int T = 2 * it;
    const int t2 = (T + 2 < NT) ? T + 2 : NT - 1;
    const int t3 = (T + 3 < NT) ? T + 3 : NT - 1;
    // ---------- P2: rd b23(T); aload P4-set; awrite A(1,1,T+1); Q(0,n0) ----
    rdBH(b23, 0, 1);
    aload(L_p4, 0, t2);
    awrite(L_p2, 1, 1);
    quad(0, 0, aH0, b01);
    LGKM0();
    BAR();
    // ---------- P3: rd aH1(T); aload P5-set; stB(0,0,T+2); Q(0,n1) ----------
    rdAH(aH1, 0, 1);
    aload(L_p5, 1, t2);
    stB(0, 0, t2);
    quad(0, 1, aH0, b23);
    BAR();
    // ---------- P4: awrite A(0,0,T+2); stB(0,1,T+2); Q(1,n1) ----------
    awrite(L_p4, 0, 0);
    quad(1, 1, aH1, b23);
    stB(0, 1, t2);
    LGKM0();
    BAR();
    // ---------- P5: rd aH0(T+1); awrite A(0,1,T+2); Q(1,n0); rd b01(T+1) ----
    rdAH(aH0, 1, 0);
    awrite(L_p5, 0, 1);
    quad(1, 0, aH1, b01);
    rdBH(b01, 1, 0);
    LGKM0();
    BAR();
    // ---------- P6: rd b23(T+1); Q(0,n0) ----------
    rdBH(b23, 1, 1);
    quad(0, 0, aH0, b01);
    BAR();
    // ---------- P7: rd aH1(T+1); aload P1-set; stB(1,0,T+3); Q(0,n1) --------
    rdAH(aH1, 1, 1);
    aload(L_p1, 0, t3);
    stB(1, 0, t3);
    quad(0, 1, aH0, b23);
    BAR();
    // ---------- P8: aload P2-set(next); Q(1,n1); stB(1,1,T+3) ----------
    aload(L_p2, 1, t3);
    quad(1, 1, aH1, b23);
    stB(1, 1, t3);
    BAR();
    // ---------- P1: rd aH0(T+2); awrite A(1,0,T+3); Q(1,n0); rd b01(T+2) ----
    rdAH(aH0, 0, 0);
    awrite(L_p1, 1, 0);
    quad(1, 0, aH1, b01);
    rdBH(b01, 0, 0);
    LGKM0();
    BAR();
  }
  WAITV(0);

  // ---- epilogue: bias + relu, fp32 stores ----
  const int row0 = bm * 256 + wr * 128;
  const int col0 = bn * 256 + wc * 64;
#pragma unroll
  for (int n = 0; n < 4; ++n) {
    const int col = col0 + n * 16 + lr;
    const float bv = bias[col];
#pragma unroll
    for (int m = 0; m < 8; ++m) {
      const int r0 = row0 + m * 16 + lk * 4;
#pragma unroll
      for (int vv = 0; vv < 4; ++vv) {
        const float val = acc[m][n][vv] + bv;
        C[(size_t)(r0 + vv) * N + col] = val > 0.f ? val : 0.f;
      }
    }
  }
}

extern "C" void kernel_launch(void* const* d_in, const int* in_sizes, int n_in,
                              void* d_out, int out_size, void* d_ws, size_t ws_size,
                              hipStream_t stream) {
  const float* x  = (const float*)d_in[0];
  const float* c0 = (const float*)d_in[1];
  const float* c1 = (const float*)d_in[2];
  const float* c2 = (const float*)d_in[3];
  const float* c3 = (const float*)d_in[4];
  const float* b  = (const float*)d_in[5];
  float* out = (float*)d_out;

  u16* mtb = (u16*)d_ws;                       // 32 MB bf16 M^T

  build_mt<<<dim3(4096), dim3(256), 0, stream>>>(c0, c1, c2, c3, mtb);
  gemm_bias_relu<<<dim3(16, 16), dim3(512), 0, stream>>>(x, mtb, b, out);
}

// Round 10
// 135.346 us; speedup vs baseline: 2.6998x; 2.6998x over previous
//
#include <hip/hip_runtime.h>
#include <hip/hip_bf16.h>
#include <stdint.h>

typedef short bf16x8 __attribute__((ext_vector_type(8)));   // 8 bf16 in 4 VGPRs
typedef float f32x4 __attribute__((ext_vector_type(4)));
typedef unsigned short u16;
typedef u16 ushort8 __attribute__((ext_vector_type(8)));

typedef __attribute__((address_space(3))) void lds_void;
typedef const __attribute__((address_space(1))) void gbl_void;

#define BAR() do { asm volatile("" ::: "memory"); __builtin_amdgcn_s_barrier(); asm volatile("" ::: "memory"); } while (0)
#define WAITV(N) asm volatile("s_waitcnt vmcnt(" #N ")" ::: "memory")
#define LGKM0() asm volatile("s_waitcnt lgkmcnt(0)" ::: "memory")

__device__ __forceinline__ u16 f2bf(float f) {
  uint32_t u = __builtin_bit_cast(uint32_t, f);
  u += 0x7fffu + ((u >> 16) & 1u);   // round-to-nearest-even
  return (u16)(u >> 16);
}

// ------------- fused prep: blocks 0..4095 build Mt, 4096..12287 cvt x -------
// build Mt[j][i] = M[i][j] (bf16 4096x4096) from TT cores; cvt: x f32->bf16.
// Both memory-bound and independent; fusing overlaps them and saves a launch.
__global__ __launch_bounds__(256) void prep_fused(
    const float* __restrict__ x, u16* __restrict__ xb,
    const float* __restrict__ c0, const float* __restrict__ c1,
    const float* __restrict__ c2, const float* __restrict__ c3,
    u16* __restrict__ Mt) {
  const int t = threadIdx.x;
  if (blockIdx.x >= 4096) {
    // ---- cvt path: 8192 blocks x 256 threads x 8 floats ----
    const int i = ((blockIdx.x - 4096) * 256 + t) * 8;
    float4 a = *(const float4*)(x + i);
    float4 b = *(const float4*)(x + i + 4);
    ushort8 o;
    o[0] = f2bf(a.x); o[1] = f2bf(a.y); o[2] = f2bf(a.z); o[3] = f2bf(a.w);
    o[4] = f2bf(b.x); o[5] = f2bf(b.y); o[6] = f2bf(b.z); o[7] = f2bf(b.w);
    *(ushort8*)(xb + i) = o;
    return;
  }
  // ---- build_mt path ----
  const int bid = blockIdx.x;
  const int j1 = bid & 7, i1 = (bid >> 3) & 7, j0 = (bid >> 6) & 7, i0 = bid >> 9;
  __shared__ float v[512];   // [i2][j2][r3]
  __shared__ float g3[512];  // copy of c3 [r3][i3][j3]
  g3[t] = c3[t];
  g3[t + 256] = c3[t + 256];
  float w2[8];
#pragma unroll
  for (int r2 = 0; r2 < 8; ++r2) {
    float s = 0.f;
#pragma unroll
    for (int r1 = 0; r1 < 8; ++r1)
      s += c0[(i0 * 8 + j0) * 8 + r1] * c1[((r1 * 8 + i1) * 8 + j1) * 8 + r2];
    w2[r2] = s;
  }
#pragma unroll
  for (int e = t; e < 512; e += 256) {
    const int r3 = e & 7, j2 = (e >> 3) & 7, i2 = e >> 6;
    float s = 0.f;
#pragma unroll
    for (int r2 = 0; r2 < 8; ++r2)
      s += w2[r2] * c2[((r2 * 8 + i2) * 8 + j2) * 8 + r3];
    v[e] = s;
  }
  __syncthreads();
  const int jr = t >> 2, ic0 = (t & 3) * 16;
  const int j2 = jr >> 3, j3 = jr & 7;
  const size_t base =
      (size_t)(j0 * 512 + j1 * 64 + jr) * 4096 + (i0 * 512 + i1 * 64) + ic0;
  ushort8 o0, o1;
#pragma unroll
  for (int q = 0; q < 16; ++q) {
    const int ic = ic0 + q, i2 = ic >> 3, i3 = ic & 7;
    float s = 0.f;
#pragma unroll
    for (int r3 = 0; r3 < 8; ++r3)
      s += v[(i2 << 6) + (j2 << 3) + r3] * g3[(r3 << 6) + (i3 << 3) + j3];
    const u16 h = f2bf(s);
    if (q < 8) o0[q] = h; else o1[q - 8] = h;
  }
  *(ushort8*)(Mt + base) = o0;
  *(ushort8*)(Mt + base + 8) = o1;
}

// ---------------- GEMM: 256x256, BK=64, R6 8-phase (reads feed next phase) --
// 8 waves (2Mx4N). Quads per tile: Q1=(mh0,nh0) Q2=(mh0,nh1) Q3=(mh1,nh1)
// Q4=(mh1,nh0). Reads issued one phase before their consuming quad; NO manual
// lgkm waits (compiler emits counted lgkmcnt -> current phase's reads drain
// UNDER the MFMA cluster). One barrier per phase. Stages placed AFTER the
// MFMA so each stage provably follows the consuming MFMA of its region's
// last read. Only bH0 wraps the quad cycle: its reload is ordered after Q4.
// vmcnt(6)@P4 forces exactly tile T+1; vmcnt(4)@P8 forces exactly tile T+2.
// Prologue stages tile0 + tile1-B, vmcnt(4) = steady state. Tail clamps
// re-stage only dead regions. Swizzle: chunk c at (c ^ (row&7)) on
// pre-swizzled global source and ds_read (rule #21).
__global__ __launch_bounds__(512, 2) void gemm_bias_relu(
    const u16* __restrict__ A, const u16* __restrict__ Bt,
    const float* __restrict__ bias, float* __restrict__ C) {
  constexpr int K = 4096, N = 4096, NT = 64;
  __shared__ __align__(16) char lds[131072];
  const int t = threadIdx.x;
  const int l = t & 63, w = t >> 6;
  const int wr = w >> 2, wc = w & 3;            // 2 x 4 wave grid
  const int lr = l & 15, lk = l >> 4;
  const int bm = blockIdx.y, bn = blockIdx.x;

  const char* gA = (const char*)A + (size_t)bm * 256 * (K * 2);
  const char* gB = (const char*)Bt + (size_t)bn * 256 * (K * 2);
  const int srow = t >> 3;                      // 0..63
  const int schunk = (t & 7) ^ (srow & 7);      // pre-swizzled source chunk
  const int sgo = srow * (K * 2) + schunk * 16;
  const int sld = t * 16;

  const int axor = (lk ^ (lr & 7)) * 16;        // kk0 chunk; kk1 = axor ^ 64
  const int aoff0 = (wr * 128 + lr) * 128 + axor;
  const int aoff1 = aoff0 ^ 64;
  const int boff0 = 65536 + (wc * 64 + lr) * 128 + axor;
  const int boff1 = boff0 ^ 64;

  auto stA = [&](int p, int h, int kt) {        // stage A M-half h of tile kt
    const char* src = gA + (size_t)(h * 128) * (K * 2) + kt * 128 + sgo;
    char* dst = lds + p * 32768 + h * 16384 + sld;
    __builtin_amdgcn_global_load_lds((gbl_void*)src, (lds_void*)dst, 16, 0, 0);
    __builtin_amdgcn_global_load_lds((gbl_void*)(src + (size_t)64 * (K * 2)),
                                     (lds_void*)(dst + 8192), 16, 0, 0);
  };
  auto stB = [&](int p, int h, int kt) {
    const char* src = gB + (size_t)(h * 128) * (K * 2) + kt * 128 + sgo;
    char* dst = lds + 65536 + p * 32768 + h * 16384 + sld;
    __builtin_amdgcn_global_load_lds((gbl_void*)src, (lds_void*)dst, 16, 0, 0);
    __builtin_amdgcn_global_load_lds((gbl_void*)(src + (size_t)64 * (K * 2)),
                                     (lds_void*)(dst + 8192), 16, 0, 0);
  };
  auto rdA = [&](int p, int off, int m) -> bf16x8 {
    return *(const bf16x8*)(lds + p * 32768 + off + m * 2048);
  };
  auto rdB = [&](int p, int off, int n) -> bf16x8 {
    return *(const bf16x8*)(lds + p * 32768 + off + n * 2048);
  };

  bf16x8 aH0[8], aH1[8], bH0[4], bH1[4];
  f32x4 acc[8][4];
#pragma unroll
  for (int m = 0; m < 8; ++m)
#pragma unroll
    for (int n = 0; n < 4; ++n) acc[m][n] = f32x4{0.f, 0.f, 0.f, 0.f};

  auto rdAH = [&](bf16x8* d, int p, int mh) {   // 4m x 2kk = 8 reads
#pragma unroll
    for (int m2 = 0; m2 < 4; ++m2) {
      d[m2 * 2 + 0] = rdA(p, aoff0, mh * 4 + m2);
      d[m2 * 2 + 1] = rdA(p, aoff1, mh * 4 + m2);
    }
  };
  auto rdBH = [&](bf16x8* d, int p, int nh) {   // 2n x 2kk = 4 reads
#pragma unroll
    for (int n2 = 0; n2 < 2; ++n2) {
      d[n2 * 2 + 0] = rdB(p, boff0, nh * 2 + n2);
      d[n2 * 2 + 1] = rdB(p, boff1, nh * 2 + n2);
    }
  };
  auto quad = [&](int mh, int nh, bf16x8* aH, bf16x8* bH) {  // 16 MFMA
    __builtin_amdgcn_s_setprio(1);
#pragma unroll
    for (int kk = 0; kk < 2; ++kk)
#pragma unroll
      for (int m2 = 0; m2 < 4; ++m2)
#pragma unroll
        for (int n2 = 0; n2 < 2; ++n2)
          acc[mh * 4 + m2][nh * 2 + n2] = __builtin_amdgcn_mfma_f32_16x16x32_bf16(
              aH[m2 * 2 + kk], bH[n2 * 2 + kk], acc[mh * 4 + m2][nh * 2 + n2], 0, 0, 0);
    __builtin_amdgcn_s_setprio(0);
  };

  // ---- prologue: tile0 (4 halves) + tile1 B halves; force tile0 ----
  stA(0, 0, 0); stA(0, 1, 0); stB(0, 0, 0); stB(0, 1, 0);
  stB(1, 0, 1); stB(1, 1, 1);
  WAITV(4);        // force tile0's 8 loads; tile1-B's 4 stay in flight
  BAR();
  // ---- P1_0: preload tile0 aH0/bH0; stage A(1,0,1) ----
  rdAH(aH0, 0, 0); rdBH(bH0, 0, 0);
  stA(1, 0, 1);
  BAR();

  for (int it = 0; it < NT / 2; ++it) {
    const int T = 2 * it;
    const int t2 = (T + 2 < NT) ? T + 2 : NT - 1;
    const int t3 = (T + 3 < NT) ? T + 3 : NT - 1;
    // ---------- P2: rd bH1(T); Q1(T); st A(1,1,T+1) ----------
    rdBH(bH1, 0, 1);
    quad(0, 0, aH0, bH0);
    stA(1, 1, T + 1);
    BAR();
    // ---------- P3: rd aH1(T); Q2(T); st B(0,0,T+2) ----------
    rdAH(aH1, 0, 1);
    quad(0, 1, aH0, bH1);
    stB(0, 0, t2);
    BAR();
    // ---------- P4: Q3(T); st B(0,1,T+2)+A(0,0,T+2); vmcnt(6) ----------
    quad(1, 1, aH1, bH1);
    stB(0, 1, t2); stA(0, 0, t2);
    WAITV(6);
    BAR();
    // ---------- P5: rd aH0(T+1); Q4(T); rd bH0(T+1); st A(0,1,T+2) ----------
    rdAH(aH0, 1, 0);
    quad(1, 0, aH1, bH0);
    rdBH(bH0, 1, 0);
    stA(0, 1, t2);
    BAR();
    // ---------- P6: rd bH1(T+1); Q1(T+1) ----------
    rdBH(bH1, 1, 1);
    quad(0, 0, aH0, bH0);
    BAR();
    // ---------- P7: rd aH1(T+1); Q2(T+1); st B(1,0,T+3) ----------
    rdAH(aH1, 1, 1);
    quad(0, 1, aH0, bH1);
    stB(1, 0, t3);
    BAR();
    // ---------- P8: Q3(T+1); st B(1,1,T+3); vmcnt(4) ----------
    quad(1, 1, aH1, bH1);
    stB(1, 1, t3);
    WAITV(4);
    BAR();
    // ---------- P1: rd aH0(T+2); Q4(T+1); rd bH0(T+2); st A(1,0,T+3) ----------
    rdAH(aH0, 0, 0);
    quad(1, 0, aH1, bH0);
    rdBH(bH0, 0, 0);
    stA(1, 0, t3);
    BAR();
  }
  WAITV(0);

  // ---- epilogue: bias + relu, fp32 stores ----
  const int row0 = bm * 256 + wr * 128;
  const int col0 = bn * 256 + wc * 64;
#pragma unroll
  for (int n = 0; n < 4; ++n) {
    const int col = col0 + n * 16 + lr;
    const float bv = bias[col];
#pragma unroll
    for (int m = 0; m < 8; ++m) {
      const int r0 = row0 + m * 16 + lk * 4;
#pragma unroll
      for (int vv = 0; vv < 4; ++vv) {
        const float val = acc[m][n][vv] + bv;
        C[(size_t)(r0 + vv) * N + col] = val > 0.f ? val : 0.f;
      }
    }
  }
}

extern "C" void kernel_launch(void* const* d_in, const int* in_sizes, int n_in,
                              void* d_out, int out_size, void* d_ws, size_t ws_size,
                              hipStream_t stream) {
  const float* x  = (const float*)d_in[0];
  const float* c0 = (const float*)d_in[1];
  const float* c1 = (const float*)d_in[2];
  const float* c2 = (const float*)d_in[3];
  const float* c3 = (const float*)d_in[4];
  const float* b  = (const float*)d_in[5];
  float* out = (float*)d_out;

  u16* xb  = (u16*)d_ws;                       // 32 MB bf16 x
  u16* mtb = xb + (size_t)4096 * 4096;         // 32 MB bf16 M^T

  prep_fused<<<dim3(4096 + 8192), dim3(256), 0, stream>>>(x, xb, c0, c1, c2, c3, mtb);
  gemm_bias_relu<<<dim3(16, 16), dim3(512), 0, stream>>>(xb, mtb, b, out);
}